// Round 1
// baseline (209.131 us; speedup 1.0000x reference)
//
#include <hip/hip_runtime.h>
#include <stdint.h>

typedef int v4i __attribute__((ext_vector_type(4)));

#define AS1(p) ((const __attribute__((address_space(1))) void*)(p))
#define AS3(p) ((__attribute__((address_space(3))) void*)(p))

// ---------------- quantize x: fp32 -> int8 ----------------
// 16 elements per thread: 4x float4 loads, 1x int4 store.
__global__ __launch_bounds__(256) void quant_x_kernel(
    const float* __restrict__ x, int8_t* __restrict__ xq,
    const float* __restrict__ s_p, const int* __restrict__ izp_p, int n16)
{
    int t = blockIdx.x * 256 + threadIdx.x;
    if (t >= n16) return;
    float s = *s_p;
    float zp = (float)(*izp_p);
    const float4* xin = (const float4*)x + (size_t)t * 4;
    int words[4];
#pragma unroll
    for (int i = 0; i < 4; ++i) {
        float4 v = xin[i];
        // round-half-even like jnp.round; exact IEEE division like the reference
        float q0 = fminf(127.f, fmaxf(-128.f, rintf(v.x / s) + zp));
        float q1 = fminf(127.f, fmaxf(-128.f, rintf(v.y / s) + zp));
        float q2 = fminf(127.f, fmaxf(-128.f, rintf(v.z / s) + zp));
        float q3 = fminf(127.f, fmaxf(-128.f, rintf(v.w / s) + zp));
        words[i] = ((int)q0 & 255) | (((int)q1 & 255) << 8) |
                   (((int)q2 & 255) << 16) | (((int)q3 & 255) << 24);
    }
    ((int4*)xq)[t] = make_int4(words[0], words[1], words[2], words[3]);
}

// ---------------- pack weight: int32 -> int8 ----------------
__global__ __launch_bounds__(256) void pack_w_kernel(
    const int* __restrict__ w, int8_t* __restrict__ w8, int n4)
{
    int t = blockIdx.x * 256 + threadIdx.x;
    if (t >= n4) return;
    int4 v = ((const int4*)w)[t];
    ((int*)w8)[t] = (v.x & 255) | ((v.y & 255) << 8) |
                    ((v.z & 255) << 16) | ((v.w & 255) << 24);
}

// ---------------- int8 GEMM: out[m][n] = (sum_k A[m][k]*B[n][k] + bias[n] - ozp)*osc
#define GM 65536
#define GN 1024
#define GK 1024

__global__ __launch_bounds__(256) void gemm_i8_kernel(
    const int8_t* __restrict__ A,   // [GM][GK] int8
    const int8_t* __restrict__ B,   // [GN][GK] int8 (weight, row n holds W[n][:])
    const int* __restrict__ bias,
    const float* __restrict__ osc_p, const int* __restrict__ ozp_p,
    float* __restrict__ out)
{
    __shared__ int8_t As[128 * 64];  // 8 KB, XOR-swizzled 16B slots
    __shared__ int8_t Bs[128 * 64];  // 8 KB

    const int tid = threadIdx.x;
    const int w = tid >> 6, l = tid & 63;
    const int wr = w >> 1, wc = w & 1;
    const int r15 = l & 15, s4 = l >> 4;

    // XCD-aware bijective mapping: bid%8 = XCD; all 8 bn-tiles of a bm group
    // land on the same XCD so the A tile is fetched from HBM once.
    const int bid = blockIdx.x;              // 0..4095
    const int xcd = bid & 7;
    const int q = bid >> 3;                  // 0..511
    const int bm0 = (((xcd << 6) + (q >> 3)) << 7);  // bm index *128
    const int bn0 = ((q & 7) << 7);

    v4i acc[4][4];
#pragma unroll
    for (int i = 0; i < 4; ++i)
#pragma unroll
        for (int j = 0; j < 4; ++j) acc[i][j] = (v4i){0, 0, 0, 0};

    // Staging: tile is 128 rows x 64 bytes. Each thread issues 2 loads for A,
    // 2 for B (16B each). LDS dest is wave-uniform base + lane*16 (linear);
    // the XOR swizzle (slot ^= (row>>1)&3) is applied on the GLOBAL source.
    const int8_t* a_src[2];
    const int8_t* b_src[2];
    int lds_base[2];
#pragma unroll
    for (int e = 0; e < 2; ++e) {
        int o = e * 4096 + w * 1024 + l * 16;   // this lane's linear LDS offset
        int row = o >> 6;
        int slot = (o >> 4) & 3;
        int gcol = ((slot ^ ((row >> 1) & 3)) << 4);
        a_src[e] = A + (size_t)(bm0 + row) * GK + gcol;
        b_src[e] = B + (size_t)(bn0 + row) * GK + gcol;
        lds_base[e] = e * 4096 + w * 1024;      // wave-uniform
    }

    // Fragment-read column with the same XOR applied.
    const int rdcol = ((s4 ^ ((r15 >> 1) & 3)) << 4);

    for (int kt = 0; kt < GK; kt += 64) {
        __builtin_amdgcn_global_load_lds(AS1(a_src[0] + kt), AS3(&As[lds_base[0]]), 16, 0, 0);
        __builtin_amdgcn_global_load_lds(AS1(a_src[1] + kt), AS3(&As[lds_base[1]]), 16, 0, 0);
        __builtin_amdgcn_global_load_lds(AS1(b_src[0] + kt), AS3(&Bs[lds_base[0]]), 16, 0, 0);
        __builtin_amdgcn_global_load_lds(AS1(b_src[1] + kt), AS3(&Bs[lds_base[1]]), 16, 0, 0);
        __syncthreads();   // compiler emits vmcnt(0) drain: staged data ready

        v4i a[4], b[4];
#pragma unroll
        for (int i = 0; i < 4; ++i)
            a[i] = *(const v4i*)&As[(wr * 64 + i * 16 + r15) * 64 + rdcol];
#pragma unroll
        for (int j = 0; j < 4; ++j)
            b[j] = *(const v4i*)&Bs[(wc * 64 + j * 16 + r15) * 64 + rdcol];

#pragma unroll
        for (int i = 0; i < 4; ++i)
#pragma unroll
            for (int j = 0; j < 4; ++j)
                acc[i][j] = __builtin_amdgcn_mfma_i32_16x16x64_i8(a[i], b[j], acc[i][j], 0, 0, 0);
        __syncthreads();
    }

    const float osc = *osc_p;
    const int ozp = *ozp_p;
    int bj[4];
#pragma unroll
    for (int j = 0; j < 4; ++j)
        bj[j] = bias[bn0 + wc * 64 + j * 16 + r15] - ozp;

    // C/D layout (16x16, dtype-independent): col = l&15, row = (l>>4)*4 + reg
#pragma unroll
    for (int i = 0; i < 4; ++i) {
        const int mrow = bm0 + wr * 64 + i * 16 + s4 * 4;
#pragma unroll
        for (int j = 0; j < 4; ++j) {
            const int n = bn0 + wc * 64 + j * 16 + r15;
            float* op = out + (size_t)mrow * GN + n;
#pragma unroll
            for (int r = 0; r < 4; ++r)
                op[(size_t)r * GN] = (float)(acc[i][j][r] + bj[j]) * osc;
        }
    }
}

extern "C" void kernel_launch(void* const* d_in, const int* in_sizes, int n_in,
                              void* d_out, int out_size, void* d_ws, size_t ws_size,
                              hipStream_t stream)
{
    const float* x        = (const float*)d_in[0];
    const int*   w_int    = (const int*)d_in[1];
    const int*   b_int    = (const int*)d_in[2];
    const float* in_scale = (const float*)d_in[3];
    const float* out_scale= (const float*)d_in[4];
    const int*   izp      = (const int*)d_in[5];
    const int*   ozp      = (const int*)d_in[6];
    float* out = (float*)d_out;

    int8_t* xq = (int8_t*)d_ws;                          // 64 MB
    int8_t* w8 = (int8_t*)d_ws + (size_t)64 * 1024 * 1024; // 1 MB

    // 16*4096*1024 = 64M elements; 16 per thread
    quant_x_kernel<<<16384, 256, 0, stream>>>(x, xq, in_scale, izp, 4194304);
    pack_w_kernel<<<1024, 256, 0, stream>>>(w_int, w8, 262144);
    gemm_i8_kernel<<<4096, 256, 0, stream>>>(xq, w8, b_int, out_scale, izp /*unused*/ == izp ? ozp : ozp, out);
}

// Round 2
// 164.573 us; speedup vs baseline: 1.2707x; 1.2707x over previous
//
#include <hip/hip_runtime.h>
#include <stdint.h>

typedef int v4i __attribute__((ext_vector_type(4)));

#define AS1(p) ((const __attribute__((address_space(1))) void*)(p))
#define AS3(p) ((__attribute__((address_space(3))) void*)(p))

// ---------------- quantize x: fp32 -> int8 ----------------
__global__ __launch_bounds__(256) void quant_x_kernel(
    const float* __restrict__ x, int8_t* __restrict__ xq,
    const float* __restrict__ s_p, const int* __restrict__ izp_p, int n16)
{
    int t = blockIdx.x * 256 + threadIdx.x;
    if (t >= n16) return;
    float s = *s_p;
    float zp = (float)(*izp_p);
    const float4* xin = (const float4*)x + (size_t)t * 4;
    int words[4];
#pragma unroll
    for (int i = 0; i < 4; ++i) {
        float4 v = xin[i];
        // round-half-even like jnp.round; exact IEEE division like the reference
        float q0 = fminf(127.f, fmaxf(-128.f, rintf(v.x / s) + zp));
        float q1 = fminf(127.f, fmaxf(-128.f, rintf(v.y / s) + zp));
        float q2 = fminf(127.f, fmaxf(-128.f, rintf(v.z / s) + zp));
        float q3 = fminf(127.f, fmaxf(-128.f, rintf(v.w / s) + zp));
        words[i] = ((int)q0 & 255) | (((int)q1 & 255) << 8) |
                   (((int)q2 & 255) << 16) | (((int)q3 & 255) << 24);
    }
    ((int4*)xq)[t] = make_int4(words[0], words[1], words[2], words[3]);
}

// ---------------- pack weight: int32 -> int8 ----------------
__global__ __launch_bounds__(256) void pack_w_kernel(
    const int* __restrict__ w, int8_t* __restrict__ w8, int n4)
{
    int t = blockIdx.x * 256 + threadIdx.x;
    if (t >= n4) return;
    int4 v = ((const int4*)w)[t];
    ((int*)w8)[t] = (v.x & 255) | ((v.y & 255) << 8) |
                    ((v.z & 255) << 16) | ((v.w & 255) << 24);
}

// ---------------- int8 GEMM, 256x256 tile, 8 waves, 4-deep LDS ring ----------------
#define GM 65536
#define GN 1024
#define GK 1024
#define NT 16   // K-tiles of 64

__global__ __launch_bounds__(512) void gemm_i8_kernel(
    const int8_t* __restrict__ A,   // [GM][GK]
    const int8_t* __restrict__ B,   // [GN][GK]
    const int* __restrict__ bias,
    const float* __restrict__ osc_p, const int* __restrict__ ozp_p,
    float* __restrict__ out)
{
    // [ring buf][A/B][256 rows x 64 B], XOR-swizzled 16B slots: phys = slot ^ ((row>>1)&3)
    __shared__ int8_t lds[4][2][16384];   // 128 KiB

    const int tid = threadIdx.x;
    const int w = tid >> 6, l = tid & 63;
    const int wm = w >> 2, wn = w & 3;          // 2x4 wave grid, per-wave out 128x64
    const int r15 = l & 15, s4 = l >> 4;

    // XCD-bijective chunked mapping: hw round-robins wg%8 across XCDs; make each
    // XCD own 128 consecutive logical blocks so the 4 bn-blocks of an A panel share L2.
    const int wg = blockIdx.x;                   // 0..1023
    const int lg = ((wg & 7) << 7) + (wg >> 3);
    const int bm0 = (lg >> 2) << 8;
    const int bn0 = (lg & 3) << 8;

    // Staging: per thread 2 A loads + 2 B loads (16 B each) per K-tile.
    // LDS dest linear (wave-uniform base + lane*16); swizzle applied to GLOBAL col.
    const int8_t* a_src[2];
    const int8_t* b_src[2];
    int st_dst[2];
#pragma unroll
    for (int e = 0; e < 2; ++e) {
        int o = ((w * 2 + e) << 10) + (l << 4);  // linear LDS offset in 16 KB matrix buf
        int row = o >> 6;                         // 0..255
        int slot = (o >> 4) & 3;
        int gcol = ((slot ^ ((row >> 1) & 3)) << 4);
        a_src[e] = A + (size_t)(bm0 + row) * GK + gcol;
        b_src[e] = B + (size_t)(bn0 + row) * GK + gcol;
        st_dst[e] = (w * 2 + e) << 10;            // wave-uniform
    }

    // Fragment read offsets (same XOR on read)
    int a_off[8], b_off[4];
#pragma unroll
    for (int i = 0; i < 8; ++i) {
        int row = wm * 128 + i * 16 + r15;
        a_off[i] = (row << 6) + ((s4 ^ ((row >> 1) & 3)) << 4);
    }
#pragma unroll
    for (int j = 0; j < 4; ++j) {
        int row = wn * 64 + j * 16 + r15;
        b_off[j] = (row << 6) + ((s4 ^ ((row >> 1) & 3)) << 4);
    }

    v4i acc[8][4];
#pragma unroll
    for (int i = 0; i < 8; ++i)
#pragma unroll
        for (int j = 0; j < 4; ++j) acc[i][j] = (v4i){0, 0, 0, 0};

#define STAGE(T, BUF) do { \
    __builtin_amdgcn_global_load_lds(AS1(a_src[0] + (T) * 64), AS3(&lds[BUF][0][st_dst[0]]), 16, 0, 0); \
    __builtin_amdgcn_global_load_lds(AS1(a_src[1] + (T) * 64), AS3(&lds[BUF][0][st_dst[1]]), 16, 0, 0); \
    __builtin_amdgcn_global_load_lds(AS1(b_src[0] + (T) * 64), AS3(&lds[BUF][1][st_dst[0]]), 16, 0, 0); \
    __builtin_amdgcn_global_load_lds(AS1(b_src[1] + (T) * 64), AS3(&lds[BUF][1][st_dst[1]]), 16, 0, 0); \
} while (0)

#define COMPUTE(BUF) do { \
    v4i af[8], bf[4]; \
    _Pragma("unroll") \
    for (int j = 0; j < 4; ++j) bf[j] = *(const v4i*)&lds[BUF][1][b_off[j]]; \
    _Pragma("unroll") \
    for (int i = 0; i < 8; ++i) af[i] = *(const v4i*)&lds[BUF][0][a_off[i]]; \
    __builtin_amdgcn_s_setprio(1); \
    _Pragma("unroll") \
    for (int i = 0; i < 8; ++i) \
    _Pragma("unroll") \
        for (int j = 0; j < 4; ++j) \
            acc[i][j] = __builtin_amdgcn_mfma_i32_16x16x64_i8(af[i], bf[j], acc[i][j], 0, 0, 0); \
    __builtin_amdgcn_s_setprio(0); \
} while (0)

    // Prologue: prefetch tiles 0,1,2 (12 loads/thread in flight)
    STAGE(0, 0); STAGE(1, 1); STAGE(2, 2);

    // Steady state: wait tile t (vmcnt 8 = tiles t+1,t+2 still in flight), barrier,
    // then stage t+3 into the buffer whose last reads completed before this barrier.
#pragma unroll 1
    for (int t = 0; t < NT - 3; ++t) {
        asm volatile("s_waitcnt vmcnt(8)" ::: "memory");
        __builtin_amdgcn_s_barrier();
        STAGE(t + 3, (t + 3) & 3);
        COMPUTE(t & 3);
    }
    // Epilogue tiles 13,14,15: drain 8 -> 4 -> 0
    asm volatile("s_waitcnt vmcnt(8)" ::: "memory");
    __builtin_amdgcn_s_barrier();
    COMPUTE(1);
    asm volatile("s_waitcnt vmcnt(4)" ::: "memory");
    __builtin_amdgcn_s_barrier();
    COMPUTE(2);
    asm volatile("s_waitcnt vmcnt(0)" ::: "memory");
    __builtin_amdgcn_s_barrier();
    COMPUTE(3);

#undef STAGE
#undef COMPUTE

    const float osc = *osc_p;
    const int ozp = *ozp_p;
    int bj[4];
#pragma unroll
    for (int j = 0; j < 4; ++j)
        bj[j] = bias[bn0 + wn * 64 + j * 16 + r15] - ozp;

    // C/D layout (16x16): col = l&15, row = (l>>4)*4 + reg
#pragma unroll
    for (int i = 0; i < 8; ++i) {
        const int mrow = bm0 + wm * 128 + i * 16 + s4 * 4;
#pragma unroll
        for (int j = 0; j < 4; ++j) {
            const int n = bn0 + wn * 64 + j * 16 + r15;
            float* op = out + (size_t)mrow * GN + n;
#pragma unroll
            for (int r = 0; r < 4; ++r)
                __builtin_nontemporal_store((float)(acc[i][j][r] + bj[j]) * osc,
                                            op + (size_t)r * GN);
        }
    }
}

extern "C" void kernel_launch(void* const* d_in, const int* in_sizes, int n_in,
                              void* d_out, int out_size, void* d_ws, size_t ws_size,
                              hipStream_t stream)
{
    const float* x         = (const float*)d_in[0];
    const int*   w_int     = (const int*)d_in[1];
    const int*   b_int     = (const int*)d_in[2];
    const float* in_scale  = (const float*)d_in[3];
    const float* out_scale = (const float*)d_in[4];
    const int*   izp       = (const int*)d_in[5];
    const int*   ozp       = (const int*)d_in[6];
    float* out = (float*)d_out;

    int8_t* xq = (int8_t*)d_ws;                            // 64 MB
    int8_t* w8 = (int8_t*)d_ws + (size_t)64 * 1024 * 1024; // 1 MB

    quant_x_kernel<<<16384, 256, 0, stream>>>(x, xq, in_scale, izp, 4194304);
    pack_w_kernel<<<1024, 256, 0, stream>>>(w_int, w8, 262144);
    gemm_i8_kernel<<<1024, 512, 0, stream>>>(xq, w8, b_int, out_scale, ozp, out);
}